// Round 6
// baseline (351.864 us; speedup 1.0000x reference)
//
#include <hip/hip_runtime.h>
#include <hip/hip_cooperative_groups.h>

namespace cg = cooperative_groups;

#define BB 2
#define LL 1024
#define DD 1024
#define HH 16
#define NC 16
#define EPSF 1e-8f

typedef __attribute__((ext_vector_type(8))) short bf16x8;
typedef __attribute__((ext_vector_type(4))) float f32x4;
typedef unsigned short u16;
typedef u16 (*tile_t)[72];

static __device__ inline u16 f2bf(float f) {
    unsigned int u = __builtin_bit_cast(unsigned int, f);
    u += 0x7fff + ((u >> 16) & 1);     // RNE
    return (u16)(u >> 16);
}
static __device__ inline float bf2f(u16 v) {
    unsigned int u = ((unsigned int)v) << 16;
    return __builtin_bit_cast(float, u);
}
static __device__ inline void gload_lds16(const u16* g, u16* l) {
    __builtin_amdgcn_global_load_lds((const __attribute__((address_space(1))) void*)g,
                                     (__attribute__((address_space(3))) void*)l, 16, 0, 0);
}

// One cooperative kernel, 512 blocks x 256 threads, 5 phases.
__global__ __launch_bounds__(256, 2) void fused_all(
    const float* __restrict__ X, const float* __restrict__ Wq,
    const float* __restrict__ Wv, const float* __restrict__ qw,
    const float* __restrict__ vw,
    u16* __restrict__ Xb, u16* __restrict__ Wqb, u16* __restrict__ Wvb,
    u16* __restrict__ Qb, u16* __restrict__ Vb, u16* __restrict__ S,
    float* __restrict__ out)
{
    cg::grid_group grid = cg::this_grid();
    __shared__ u16 smem[18432];    // 36 KB arena, aliased per phase

    const int tid = threadIdx.x, bid = blockIdx.x;
    const int w = tid >> 6, lane = tid & 63;
    const int quad = lane >> 4, l16 = lane & 15;

    // ---------- Phase 0: fp32 -> bf16 convert (X 2M | Wq 1M | Wv 1M)
    {
        int i0 = (bid * 256 + tid) * 4;
        #pragma unroll
        for (int p = 0; p < 8; ++p) {
            int i = i0 + p * 524288;
            const float* s; u16* d; int off;
            if (i < 2*1024*1024)      { s = X;  d = Xb;  off = i; }
            else if (i < 3*1024*1024) { s = Wq; d = Wqb; off = i - 2*1024*1024; }
            else                      { s = Wv; d = Wvb; off = i - 3*1024*1024; }
            float4 v = *(const float4*)(s + off);
            ushort4 o;
            o.x = f2bf(v.x); o.y = f2bf(v.y); o.z = f2bf(v.z); o.w = f2bf(v.w);
            *(ushort4*)(d + off) = o;
        }
    }
    grid.sync();

    // ---------- Phase 1: bf16 MFMA GEMM (128x64 tile, BK=64) + fused RMSNorm
    {
        const int z = bid >> 8, rem = bid & 255;
        const int n0 = (rem & 15) * 64, m0 = (rem >> 4) * 128;
        const u16* Wb = z ? Wvb : Wqb;
        const float* nw = z ? vw : qw;
        u16* Y = z ? Vb : Qb;
        u16* As0 = smem;            // 128*32
        u16* As1 = smem + 4096;
        u16* Bs0 = smem + 8192;     // 64*32
        u16* Bs1 = smem + 10240;

        const int lrow = lane >> 2, lcol = (lane & 3) * 8;
        const u16* gA0 = Xb + (size_t)(m0 + w*16 + lrow) * DD + lcol;
        const u16* gA1 = gA0 + (size_t)64 * DD;
        const u16* gB0 = Wb + (size_t)(n0 + w*16 + lrow) * DD + lcol;
        u16* lA0_0 = &As0[(w*16) * 32];      u16* lA0_1 = &As1[(w*16) * 32];
        u16* lA1_0 = &As0[(64 + w*16) * 32]; u16* lA1_1 = &As1[(64 + w*16) * 32];
        u16* lB0_0 = &Bs0[(w*16) * 32];      u16* lB0_1 = &Bs1[(w*16) * 32];

        f32x4 acc[2][4] = {};
        for (int k0 = 0; k0 < DD; k0 += 64) {
            gload_lds16(gA0 + k0,      lA0_0);
            gload_lds16(gA0 + k0 + 32, lA0_1);
            gload_lds16(gA1 + k0,      lA1_0);
            gload_lds16(gA1 + k0 + 32, lA1_1);
            gload_lds16(gB0 + k0,      lB0_0);
            gload_lds16(gB0 + k0 + 32, lB0_1);
            __syncthreads();
            #pragma unroll
            for (int hh = 0; hh < 2; ++hh) {
                const u16* Ah = hh ? As1 : As0;
                const u16* Bh = hh ? Bs1 : Bs0;
                bf16x8 af[2], bfr[4];
                #pragma unroll
                for (int i = 0; i < 2; ++i)
                    af[i] = *(const bf16x8*)&Ah[(w*32 + i*16 + l16) * 32 + quad*8];
                #pragma unroll
                for (int j = 0; j < 4; ++j)
                    bfr[j] = *(const bf16x8*)&Bh[(j*16 + l16) * 32 + quad*8];
                #pragma unroll
                for (int i = 0; i < 2; ++i)
                    #pragma unroll
                    for (int j = 0; j < 4; ++j)
                        acc[i][j] = __builtin_amdgcn_mfma_f32_16x16x32_bf16(af[i], bfr[j], acc[i][j], 0, 0, 0);
            }
            __syncthreads();
        }
        float wv4[4];
        #pragma unroll
        for (int j = 0; j < 4; ++j) wv4[j] = nw[n0 + j*16 + l16];
        #pragma unroll
        for (int i = 0; i < 2; ++i) {
            float ss[4];
            #pragma unroll
            for (int r = 0; r < 4; ++r) {
                float s = 0.f;
                #pragma unroll
                for (int j = 0; j < 4; ++j) s += acc[i][j][r] * acc[i][j][r];
                ss[r] = s;
            }
            #pragma unroll
            for (int off = 1; off < 16; off <<= 1)
                #pragma unroll
                for (int r = 0; r < 4; ++r) ss[r] += __shfl_xor(ss[r], off, 64);
            float sc[4];
            #pragma unroll
            for (int r = 0; r < 4; ++r) sc[r] = rsqrtf(ss[r] * (1.f/64.f) + EPSF);
            #pragma unroll
            for (int r = 0; r < 4; ++r) {
                u16* yp = Y + (size_t)(m0 + w*32 + i*16 + quad*4 + r) * DD + n0;
                #pragma unroll
                for (int j = 0; j < 4; ++j)
                    yp[j*16 + l16] = f2bf(acc[i][j][r] * sc[r] * wv4[j]);
            }
        }
    }
    grid.sync();

    // ---------- Phase 2: per-chunk S_c^T[e][d] = sum_l V[l][e] K[l][d]
    {
        const int bh = bid >> 4, c = bid & 15;
        const int h = bh & 15, b = bh >> 4;
        tile_t Kt = (tile_t)smem;            // [d][l]
        tile_t Vt = (tile_t)(smem + 4608);   // [e][l]
        {
            const int row = tid >> 2, q = tid & 3;
            size_t gbase = (size_t)(b*LL + c*64 + row) * DD + h*64 + q*16;
            u16 kk[16], vv[16];
            #pragma unroll
            for (int i = 0; i < 16; i += 4) {
                *(ushort4*)&kk[i] = *(const ushort4*)(Xb + gbase + i);
                *(ushort4*)&vv[i] = *(const ushort4*)(Vb + gbase + i);
            }
            #pragma unroll
            for (int i = 0; i < 16; ++i) {
                Kt[q*16 + i][row] = kk[i];
                Vt[q*16 + i][row] = vv[i];
            }
        }
        __syncthreads();
        const int me = (w & 1) * 32, nd = (w >> 1) * 32;
        f32x4 acc[2][2] = {};
        #pragma unroll
        for (int k0 = 0; k0 < 64; k0 += 32) {
            bf16x8 av[2], bv[2];
            #pragma unroll
            for (int i = 0; i < 2; ++i)
                av[i] = *(const bf16x8*)&Vt[me + i*16 + l16][k0 + quad*8];
            #pragma unroll
            for (int j = 0; j < 2; ++j)
                bv[j] = *(const bf16x8*)&Kt[nd + j*16 + l16][k0 + quad*8];
            #pragma unroll
            for (int i = 0; i < 2; ++i)
                #pragma unroll
                for (int j = 0; j < 2; ++j)
                    acc[i][j] = __builtin_amdgcn_mfma_f32_16x16x32_bf16(av[i], bv[j], acc[i][j], 0, 0, 0);
        }
        // flat C-layout store: addr = w*1024 + (i*2+j)*256 + r*64 + lane
        u16* Sp = S + ((size_t)bid << 12) + w*1024;
        #pragma unroll
        for (int i = 0; i < 2; ++i)
            #pragma unroll
            for (int j = 0; j < 2; ++j)
                #pragma unroll
                for (int r = 0; r < 4; ++r)
                    Sp[(i*2 + j)*256 + r*64 + lane] = f2bf(acc[i][j][r]);
    }
    grid.sync();

    // ---------- Phase 3: positionwise exclusive prefix scan over 16 chunks
    {
        const int gid = bid * 256 + tid;          // 0..131071
        const int bh = gid >> 12, pos = gid & 4095;
        u16* base = S + (size_t)bh * 65536 + pos;
        float run = 0.f;
        #pragma unroll
        for (int c = 0; c < NC; ++c) {
            float v = bf2f(base[c * 4096]);
            base[c * 4096] = f2bf(run);
            run += v;
        }
    }
    grid.sync();

    // ---------- Phase 4: out = tril(Q K^T) @ V + Q @ S0, per chunk
    {
        const int c = bid & 15, bh = bid >> 4;
        const int h = bh & 15, b = bh >> 4;
        tile_t Qs = (tile_t)smem;             // [l][d]
        tile_t Ks = (tile_t)(smem + 4608);    // [l'][d] -> later Ps [l][l']
        tile_t Vt = (tile_t)(smem + 9216);    // [e][l']
        tile_t St = (tile_t)(smem + 13824);   // [e][d]
        {
            const int row = tid >> 2, q = tid & 3;
            size_t gbase = (size_t)(b*LL + c*64 + row) * DD + h*64 + q*16;
            u16 vv[16];
            #pragma unroll
            for (int i = 0; i < 16; i += 4) {
                *(ushort4*)&Qs[row][q*16 + i] = *(const ushort4*)(Qb + gbase + i);
                *(ushort4*)&Ks[row][q*16 + i] = *(const ushort4*)(Xb + gbase + i);
                *(ushort4*)&vv[i] = *(const ushort4*)(Vb + gbase + i);
            }
            #pragma unroll
            for (int i = 0; i < 16; ++i)
                Vt[q*16 + i][row] = vv[i];
            // coalesced 16B reads of the flat C-layout prefix
            const u16* Sc = S + ((size_t)bid << 12);
            #pragma unroll
            for (int jj = 0; jj < 4; ++jj) {
                int f = (tid + jj*256) * 4;
                ushort4 sv = *(const ushort4*)(Sc + f);
                int w_ = f >> 10, fij = (f >> 8) & 3, r_ = (f >> 6) & 3, ln = f & 63;
                int e = (w_ & 1)*32 + (fij >> 1)*16 + (ln >> 4)*4 + r_;
                int d = (w_ >> 1)*32 + (fij & 1)*16 + (ln & 15);
                *(ushort4*)&St[e][d] = sv;
            }
        }
        __syncthreads();
        const int mo = (w & 1) * 32, no = (w >> 1) * 32;
        // P = Q K^T, causal-masked, bf16 (Ps aliases Ks)
        f32x4 pacc[2][2] = {};
        #pragma unroll
        for (int k0 = 0; k0 < 64; k0 += 32) {
            bf16x8 aq[2], bk[2];
            #pragma unroll
            for (int i = 0; i < 2; ++i)
                aq[i] = *(const bf16x8*)&Qs[mo + i*16 + l16][k0 + quad*8];
            #pragma unroll
            for (int j = 0; j < 2; ++j)
                bk[j] = *(const bf16x8*)&Ks[no + j*16 + l16][k0 + quad*8];
            #pragma unroll
            for (int i = 0; i < 2; ++i)
                #pragma unroll
                for (int j = 0; j < 2; ++j)
                    pacc[i][j] = __builtin_amdgcn_mfma_f32_16x16x32_bf16(aq[i], bk[j], pacc[i][j], 0, 0, 0);
        }
        __syncthreads();
        #pragma unroll
        for (int i = 0; i < 2; ++i)
            #pragma unroll
            for (int j = 0; j < 2; ++j)
                #pragma unroll
                for (int r = 0; r < 4; ++r) {
                    int l  = mo + i*16 + quad*4 + r;
                    int lp = no + j*16 + l16;
                    Ks[l][lp] = (lp <= l) ? f2bf(pacc[i][j][r]) : (u16)0;
                }
        __syncthreads();
        f32x4 acc[2][2] = {};
        #pragma unroll
        for (int k0 = 0; k0 < 64; k0 += 32) {
            bf16x8 a1[2], b1[2], a2[2], b2[2];
            #pragma unroll
            for (int i = 0; i < 2; ++i) {
                a1[i] = *(const bf16x8*)&Ks[mo + i*16 + l16][k0 + quad*8];
                a2[i] = *(const bf16x8*)&Qs[mo + i*16 + l16][k0 + quad*8];
            }
            #pragma unroll
            for (int j = 0; j < 2; ++j) {
                b1[j] = *(const bf16x8*)&Vt[no + j*16 + l16][k0 + quad*8];
                b2[j] = *(const bf16x8*)&St[no + j*16 + l16][k0 + quad*8];
            }
            #pragma unroll
            for (int i = 0; i < 2; ++i)
                #pragma unroll
                for (int j = 0; j < 2; ++j) {
                    acc[i][j] = __builtin_amdgcn_mfma_f32_16x16x32_bf16(a1[i], b1[j], acc[i][j], 0, 0, 0);
                    acc[i][j] = __builtin_amdgcn_mfma_f32_16x16x32_bf16(a2[i], b2[j], acc[i][j], 0, 0, 0);
                }
        }
        float* op = out + (size_t)(b*LL + c*64) * DD + h*64;
        #pragma unroll
        for (int i = 0; i < 2; ++i)
            #pragma unroll
            for (int j = 0; j < 2; ++j)
                #pragma unroll
                for (int r = 0; r < 4; ++r)
                    op[(size_t)(mo + i*16 + quad*4 + r) * DD + no + j*16 + l16] = acc[i][j][r];
    }
}

extern "C" void kernel_launch(void* const* d_in, const int* in_sizes, int n_in,
                              void* d_out, int out_size, void* d_ws, size_t ws_size,
                              hipStream_t stream) {
    const float* X  = (const float*)d_in[0];
    const float* Wq = (const float*)d_in[1];
    const float* Wv = (const float*)d_in[2];
    const float* qw = (const float*)d_in[3];
    const float* vw = (const float*)d_in[4];
    float* out = (float*)d_out;

    u16* Xb  = (u16*)d_ws;                        // 2M u16
    u16* Wqb = Xb  + (size_t)2*1024*1024;         // 1M
    u16* Wvb = Wqb + (size_t)1024*1024;           // 1M
    u16* Qb  = Wvb + (size_t)1024*1024;           // 2M
    u16* Vb  = Qb  + (size_t)2*1024*1024;         // 2M
    u16* S   = Vb  + (size_t)2*1024*1024;         // 2M u16

    void* args[] = { (void*)&X, (void*)&Wq, (void*)&Wv, (void*)&qw, (void*)&vw,
                     (void*)&Xb, (void*)&Wqb, (void*)&Wvb, (void*)&Qb, (void*)&Vb,
                     (void*)&S, (void*)&out };
    hipLaunchCooperativeKernel((void*)fused_all, dim3(512), dim3(256),
                               args, 0, stream);
}

// Round 7
// 113.815 us; speedup vs baseline: 3.0915x; 3.0915x over previous
//
#include <hip/hip_runtime.h>

#define BB 2
#define LL 1024
#define DD 1024
#define HH 16
#define NC 16
#define EPSF 1e-8f

typedef __attribute__((ext_vector_type(8))) short bf16x8;
typedef __attribute__((ext_vector_type(4))) float f32x4;
typedef unsigned short u16;

static __device__ inline u16 f2bf(float f) {
    unsigned int u = __builtin_bit_cast(unsigned int, f);
    u += 0x7fff + ((u >> 16) & 1);     // RNE
    return (u16)(u >> 16);
}

static __device__ inline void gload_lds16(const u16* g, u16* l) {
    __builtin_amdgcn_global_load_lds((const __attribute__((address_space(1))) void*)g,
                                     (__attribute__((address_space(3))) void*)l, 16, 0, 0);
}

// ---------------- fp32 -> bf16 convert: X (2M), Wq (1M), Wv (1M)
__global__ __launch_bounds__(256) void cvt_k(const float* __restrict__ X,
                                             const float* __restrict__ Wq,
                                             const float* __restrict__ Wv,
                                             u16* __restrict__ Xb,
                                             u16* __restrict__ Wqb,
                                             u16* __restrict__ Wvb)
{
    int i = (blockIdx.x * 256 + threadIdx.x) * 4;
    const float* s; u16* d; int off;
    if (i < 2*1024*1024)      { s = X;  d = Xb;  off = i; }
    else if (i < 3*1024*1024) { s = Wq; d = Wqb; off = i - 2*1024*1024; }
    else                      { s = Wv; d = Wvb; off = i - 3*1024*1024; }
    float4 v = *(const float4*)(s + off);
    ushort4 o;
    o.x = f2bf(v.x); o.y = f2bf(v.y); o.z = f2bf(v.z); o.w = f2bf(v.w);
    *(ushort4*)(d + off) = o;
}

// ---------------- bf16 MFMA GEMM (m97 structure: 128x128 tile, BK=32) +
// fused per-head RMSNorm, bf16 out. Waves 2x2; wave quadrant = 64 rows x 64
// cols = one head, so the d=64 RMS reduction is an in-register 16-lane shuffle.
__global__ __launch_bounds__(256) void gemm_fused(const u16* __restrict__ Xb,
                                                  const u16* __restrict__ Wqb,
                                                  const u16* __restrict__ Wvb,
                                                  const float* __restrict__ qw,
                                                  const float* __restrict__ vw,
                                                  u16* __restrict__ Qb,
                                                  u16* __restrict__ Vb)
{
    const int K = DD, N = DD;
    const u16* W = blockIdx.z ? Wvb : Wqb;
    const float* nw = blockIdx.z ? vw : qw;
    u16* Y = blockIdx.z ? Vb : Qb;
    __shared__ u16 As[128 * 32];
    __shared__ u16 Bs[128 * 32];

    const int tid = threadIdx.x, w = tid >> 6, lane = tid & 63;
    const int quad = lane >> 4, l16 = lane & 15;
    const int wm = w & 1, wn = w >> 1;
    const int m0 = blockIdx.y * 128, n0 = blockIdx.x * 128;
    const int lrow = lane >> 2, lcol = (lane & 3) * 8;

    const u16* gA0 = Xb + (size_t)(m0 + w*16 + lrow) * K + lcol;
    const u16* gA1 = gA0 + (size_t)64 * K;
    const u16* gB0 = W + (size_t)(n0 + w*16 + lrow) * K + lcol;
    const u16* gB1 = gB0 + (size_t)64 * K;
    u16* lA0 = &As[(w*16) * 32];
    u16* lA1 = &As[(64 + w*16) * 32];
    u16* lB0 = &Bs[(w*16) * 32];
    u16* lB1 = &Bs[(64 + w*16) * 32];

    f32x4 acc[4][4] = {};
    for (int k0 = 0; k0 < K; k0 += 32) {
        gload_lds16(gA0 + k0, lA0);
        gload_lds16(gA1 + k0, lA1);
        gload_lds16(gB0 + k0, lB0);
        gload_lds16(gB1 + k0, lB1);
        __syncthreads();
        bf16x8 af[4], bfr[4];
        #pragma unroll
        for (int i = 0; i < 4; ++i)
            af[i] = *(const bf16x8*)&As[(wm*64 + i*16 + l16) * 32 + quad*8];
        #pragma unroll
        for (int j = 0; j < 4; ++j)
            bfr[j] = *(const bf16x8*)&Bs[(wn*64 + j*16 + l16) * 32 + quad*8];
        #pragma unroll
        for (int i = 0; i < 4; ++i)
            #pragma unroll
            for (int j = 0; j < 4; ++j)
                acc[i][j] = __builtin_amdgcn_mfma_f32_16x16x32_bf16(af[i], bfr[j], acc[i][j], 0, 0, 0);
        __syncthreads();
    }

    // fused RMSNorm: row = m0+wm*64+i*16+quad*4+r ; col = n0+wn*64+j*16+l16
    float wv4[4];
    #pragma unroll
    for (int j = 0; j < 4; ++j) wv4[j] = nw[n0 + wn*64 + j*16 + l16];
    #pragma unroll
    for (int i = 0; i < 4; ++i) {
        float ss[4];
        #pragma unroll
        for (int r = 0; r < 4; ++r) {
            float s = 0.f;
            #pragma unroll
            for (int j = 0; j < 4; ++j) s += acc[i][j][r] * acc[i][j][r];
            ss[r] = s;
        }
        #pragma unroll
        for (int off = 1; off < 16; off <<= 1)
            #pragma unroll
            for (int r = 0; r < 4; ++r) ss[r] += __shfl_xor(ss[r], off, 64);
        float sc[4];
        #pragma unroll
        for (int r = 0; r < 4; ++r) sc[r] = rsqrtf(ss[r] * (1.f/64.f) + EPSF);
        #pragma unroll
        for (int r = 0; r < 4; ++r) {
            u16* yp = Y + (size_t)(m0 + wm*64 + i*16 + quad*4 + r) * N + n0 + wn*64;
            #pragma unroll
            for (int j = 0; j < 4; ++j)
                yp[j*16 + l16] = f2bf(acc[i][r >= 0 ? j : j][r] * sc[r] * wv4[j]);
        }
    }
}

// ---------------- fused chunk-KV + exclusive prefix scan, double-buffered.
// grid 128 = (b,h) x (e-half, d-half). One barrier per chunk iteration.
// S stored bf16 in flat MFMA C-layout: offset = t*1024 + w*256 + r*64 + lane
__global__ __launch_bounds__(256) void kv_scan(const u16* __restrict__ Xb,
                                               const u16* __restrict__ Vb,
                                               u16* __restrict__ S)
{
    const int t = blockIdx.x & 3, bh = blockIdx.x >> 2;
    const int et = t & 1, dt = t >> 1;
    const int h = bh & 15, b = bh >> 4;
    __shared__ u16 Kt[2][32][72];
    __shared__ u16 Vt[2][32][72];
    const int tid = threadIdx.x, w = tid >> 6, lane = tid & 63;
    const int quad = lane >> 4, l16 = lane & 15;
    const int esub = (w & 1) * 16, dsub = (w >> 1) * 16;
    const int half = tid >> 7, hrow = (tid & 127) >> 1, hq = tid & 1;
    const u16* gsrc = (half ? Vb : Xb) + (size_t)(b*LL + hrow) * DD
                      + h*64 + (half ? et : dt) * 32 + hq*16;
    u16 (*Tb)[32][72] = half ? Vt : Kt;
    ushort4 rr[4];

    auto loadc = [&](int c) {
        const u16* p = gsrc + (size_t)c * 64 * DD;
        rr[0] = *(const ushort4*)(p);      rr[1] = *(const ushort4*)(p + 4);
        rr[2] = *(const ushort4*)(p + 8);  rr[3] = *(const ushort4*)(p + 12);
    };
    auto writec = [&](int buf) {
        #pragma unroll
        for (int i = 0; i < 16; ++i)
            Tb[buf][hq*16 + i][hrow] = ((const u16*)rr)[i];
    };

    loadc(0); writec(0); loadc(1);
    __syncthreads();
    f32x4 acc = {};
    for (int c = 0; c < NC; ++c) {
        const int cur = c & 1;
        if (c + 1 < NC) writec(1 - cur);
        if (c + 2 < NC) loadc(c + 2);
        u16* Sp = S + (((size_t)(bh*NC + c)) << 12) + t*1024 + w*256;
        #pragma unroll
        for (int r = 0; r < 4; ++r) Sp[r*64 + lane] = f2bf(acc[r]);
        #pragma unroll
        for (int k0 = 0; k0 < 64; k0 += 32) {
            bf16x8 av = *(const bf16x8*)&Vt[cur][esub + l16][k0 + quad*8];
            bf16x8 bv = *(const bf16x8*)&Kt[cur][dsub + l16][k0 + quad*8];
            acc = __builtin_amdgcn_mfma_f32_16x16x32_bf16(av, bv, acc, 0, 0, 0);
        }
        __syncthreads();
    }
}

// ---------------- out = tril(Q K^T) @ V + Q @ S0, per chunk, MFMA.
__global__ __launch_bounds__(256) void out_k(const u16* __restrict__ Xb,
                                             const u16* __restrict__ Qb,
                                             const u16* __restrict__ Vb,
                                             const u16* __restrict__ S,
                                             float* __restrict__ out)
{
    const int c = blockIdx.x & 15, bh = blockIdx.x >> 4;
    const int h = bh & 15, b = bh >> 4;
    __shared__ u16 Qs[64][72];   // [l][d]
    __shared__ u16 Ks[64][72];   // [l'][d] -> later Ps [l][l']
    __shared__ u16 Vt[64][72];   // [e][l']
    __shared__ u16 St[64][72];   // [e][d]
    const int tid = threadIdx.x;
    {
        const int row = tid >> 2, q = tid & 3;
        size_t gbase = (size_t)(b*LL + c*64 + row) * DD + h*64 + q*16;
        u16 vv[16];
        #pragma unroll
        for (int i = 0; i < 16; i += 4) {
            *(ushort4*)&Qs[row][q*16 + i] = *(const ushort4*)(Qb + gbase + i);
            *(ushort4*)&Ks[row][q*16 + i] = *(const ushort4*)(Xb + gbase + i);
            *(ushort4*)&vv[i] = *(const ushort4*)(Vb + gbase + i);
        }
        #pragma unroll
        for (int i = 0; i < 16; ++i)
            Vt[q*16 + i][row] = vv[i];
        const u16* Sc = S + (((size_t)(bh*NC + c)) << 12);
        #pragma unroll
        for (int j = 0; j < 4; ++j) {
            int f = (tid + j*256) * 4;
            ushort4 sv = *(const ushort4*)(Sc + f);
            int tt = f >> 10, ww = (f >> 8) & 3, rr_ = (f >> 6) & 3, ln = f & 63;
            int e = (tt & 1)*32 + (ww & 1)*16 + (ln >> 4)*4 + rr_;
            int d = (tt >> 1)*32 + ((ww >> 1) & 1)*16 + (ln & 15);
            *(ushort4*)&St[e][d] = sv;
        }
    }
    __syncthreads();
    const int w = tid >> 6, lane = tid & 63, quad = lane >> 4, l16 = lane & 15;
    const int mo = (w & 1) * 32, no = (w >> 1) * 32;

    f32x4 pacc[2][2] = {};
    #pragma unroll
    for (int k0 = 0; k0 < 64; k0 += 32) {
        bf16x8 aq[2], bk[2];
        #pragma unroll
        for (int i = 0; i < 2; ++i)
            aq[i] = *(const bf16x8*)&Qs[mo + i*16 + l16][k0 + quad*8];
        #pragma unroll
        for (int j = 0; j < 2; ++j)
            bk[j] = *(const bf16x8*)&Ks[no + j*16 + l16][k0 + quad*8];
        #pragma unroll
        for (int i = 0; i < 2; ++i)
            #pragma unroll
            for (int j = 0; j < 2; ++j)
                pacc[i][j] = __builtin_amdgcn_mfma_f32_16x16x32_bf16(aq[i], bk[j], pacc[i][j], 0, 0, 0);
    }
    __syncthreads();
    #pragma unroll
    for (int i = 0; i < 2; ++i)
        #pragma unroll
        for (int j = 0; j < 2; ++j)
            #pragma unroll
            for (int r = 0; r < 4; ++r) {
                int l  = mo + i*16 + quad*4 + r;
                int lp = no + j*16 + l16;
                Ks[l][lp] = (lp <= l) ? f2bf(pacc[i][j][r]) : (u16)0;
            }
    __syncthreads();

    f32x4 acc[2][2] = {};
    #pragma unroll
    for (int k0 = 0; k0 < 64; k0 += 32) {
        bf16x8 a1[2], b1[2], a2[2], b2[2];
        #pragma unroll
        for (int i = 0; i < 2; ++i) {
            a1[i] = *(const bf16x8*)&Ks[mo + i*16 + l16][k0 + quad*8];
            a2[i] = *(const bf16x8*)&Qs[mo + i*16 + l16][k0 + quad*8];
        }
        #pragma unroll
        for (int j = 0; j < 2; ++j) {
            b1[j] = *(const bf16x8*)&Vt[no + j*16 + l16][k0 + quad*8];
            b2[j] = *(const bf16x8*)&St[no + j*16 + l16][k0 + quad*8];
        }
        #pragma unroll
        for (int i = 0; i < 2; ++i)
            #pragma unroll
            for (int j = 0; j < 2; ++j) {
                acc[i][j] = __builtin_amdgcn_mfma_f32_16x16x32_bf16(a1[i], b1[j], acc[i][j], 0, 0, 0);
                acc[i][j] = __builtin_amdgcn_mfma_f32_16x16x32_bf16(a2[i], b2[j], acc[i][j], 0, 0, 0);
            }
    }
    float* op = out + (size_t)(b*LL + c*64) * DD + h*64;
    #pragma unroll
    for (int i = 0; i < 2; ++i)
        #pragma unroll
        for (int j = 0; j < 2; ++j)
            #pragma unroll
            for (int r = 0; r < 4; ++r)
                op[(size_t)(mo + i*16 + quad*4 + r) * DD + no + j*16 + l16] = acc[i][j][r];
}

extern "C" void kernel_launch(void* const* d_in, const int* in_sizes, int n_in,
                              void* d_out, int out_size, void* d_ws, size_t ws_size,
                              hipStream_t stream) {
    const float* X  = (const float*)d_in[0];
    const float* Wq = (const float*)d_in[1];
    const float* Wv = (const float*)d_in[2];
    const float* qw = (const float*)d_in[3];
    const float* vw = (const float*)d_in[4];
    float* out = (float*)d_out;

    u16* Xb  = (u16*)d_ws;                        // 2M u16
    u16* Wqb = Xb  + (size_t)2*1024*1024;         // 1M
    u16* Wvb = Wqb + (size_t)1024*1024;           // 1M
    u16* Qb  = Wvb + (size_t)1024*1024;           // 2M
    u16* Vb  = Qb  + (size_t)2*1024*1024;         // 2M
    u16* S   = Vb  + (size_t)2*1024*1024;         // 2M u16

    cvt_k<<<4096, 256, 0, stream>>>(X, Wq, Wv, Xb, Wqb, Wvb);
    gemm_fused<<<dim3(8, 16, 2), 256, 0, stream>>>(Xb, Wqb, Wvb, qw, vw, Qb, Vb);
    kv_scan<<<128, 256, 0, stream>>>(Xb, Vb, S);
    out_k<<<BB*HH*NC, 256, 0, stream>>>(Xb, Qb, Vb, S, out);
}

// Round 8
// 112.783 us; speedup vs baseline: 3.1198x; 1.0092x over previous
//
#include <hip/hip_runtime.h>

#define BB 2
#define LL 1024
#define DD 1024
#define HH 16
#define NC 16
#define EPSF 1e-8f

typedef __attribute__((ext_vector_type(8))) short bf16x8;
typedef __attribute__((ext_vector_type(4))) float f32x4;
typedef unsigned short u16;

static __device__ inline u16 f2bf(float f) {
    unsigned int u = __builtin_bit_cast(unsigned int, f);
    u += 0x7fff + ((u >> 16) & 1);     // RNE
    return (u16)(u >> 16);
}

static __device__ inline void gload_lds16(const u16* g, u16* l) {
    __builtin_amdgcn_global_load_lds((const __attribute__((address_space(1))) void*)g,
                                     (__attribute__((address_space(3))) void*)l, 16, 0, 0);
}

// ---------------- fp32 -> bf16 convert: X (2M), Wq (1M), Wv (1M)
__global__ __launch_bounds__(256) void cvt_k(const float* __restrict__ X,
                                             const float* __restrict__ Wq,
                                             const float* __restrict__ Wv,
                                             u16* __restrict__ Xb,
                                             u16* __restrict__ Wqb,
                                             u16* __restrict__ Wvb)
{
    int i = (blockIdx.x * 256 + threadIdx.x) * 4;
    const float* s; u16* d; int off;
    if (i < 2*1024*1024)      { s = X;  d = Xb;  off = i; }
    else if (i < 3*1024*1024) { s = Wq; d = Wqb; off = i - 2*1024*1024; }
    else                      { s = Wv; d = Wvb; off = i - 3*1024*1024; }
    float4 v = *(const float4*)(s + off);
    ushort4 o;
    o.x = f2bf(v.x); o.y = f2bf(v.y); o.z = f2bf(v.z); o.w = f2bf(v.w);
    *(ushort4*)(d + off) = o;
}

// ---------------- bf16 MFMA GEMM + fused per-head RMSNorm, bf16 out.
// 128(M) x 64(N) tile, BK=64 via two ping LDS slices; 512 blocks (2/CU).
// Wave w owns rows w*32..+31 x all 64 cols -> d=64 RMS reduce is in-register.
__global__ __launch_bounds__(256) void gemm_fused(const u16* __restrict__ Xb,
                                                  const u16* __restrict__ Wqb,
                                                  const u16* __restrict__ Wvb,
                                                  const float* __restrict__ qw,
                                                  const float* __restrict__ vw,
                                                  u16* __restrict__ Qb,
                                                  u16* __restrict__ Vb)
{
    const int K = DD, N = DD;
    const u16* W = blockIdx.z ? Wvb : Wqb;
    const float* nw = blockIdx.z ? vw : qw;
    u16* Y = blockIdx.z ? Vb : Qb;
    __shared__ u16 As0[128 * 32], As1[128 * 32];
    __shared__ u16 Bs0[64 * 32],  Bs1[64 * 32];

    const int tid = threadIdx.x, w = tid >> 6, lane = tid & 63;
    const int quad = lane >> 4, l16 = lane & 15;
    const int m0 = blockIdx.y * 128, n0 = blockIdx.x * 64;
    const int lrow = lane >> 2, lcol = (lane & 3) * 8;

    const u16* gA0 = Xb + (size_t)(m0 + w*16 + lrow) * K + lcol;
    const u16* gA1 = gA0 + (size_t)64 * K;
    const u16* gB0 = W + (size_t)(n0 + w*16 + lrow) * K + lcol;
    u16* lA0_0 = &As0[(w*16) * 32];      u16* lA0_1 = &As1[(w*16) * 32];
    u16* lA1_0 = &As0[(64 + w*16) * 32]; u16* lA1_1 = &As1[(64 + w*16) * 32];
    u16* lB0_0 = &Bs0[(w*16) * 32];      u16* lB0_1 = &Bs1[(w*16) * 32];

    f32x4 acc[2][4] = {};
    for (int k0 = 0; k0 < K; k0 += 64) {
        gload_lds16(gA0 + k0,      lA0_0);
        gload_lds16(gA0 + k0 + 32, lA0_1);
        gload_lds16(gA1 + k0,      lA1_0);
        gload_lds16(gA1 + k0 + 32, lA1_1);
        gload_lds16(gB0 + k0,      lB0_0);
        gload_lds16(gB0 + k0 + 32, lB0_1);
        __syncthreads();
        #pragma unroll
        for (int hh = 0; hh < 2; ++hh) {
            const u16* Ah = hh ? As1 : As0;
            const u16* Bh = hh ? Bs1 : Bs0;
            bf16x8 af[2], bfr[4];
            #pragma unroll
            for (int i = 0; i < 2; ++i)
                af[i] = *(const bf16x8*)&Ah[(w*32 + i*16 + l16) * 32 + quad*8];
            #pragma unroll
            for (int j = 0; j < 4; ++j)
                bfr[j] = *(const bf16x8*)&Bh[(j*16 + l16) * 32 + quad*8];
            #pragma unroll
            for (int i = 0; i < 2; ++i)
                #pragma unroll
                for (int j = 0; j < 4; ++j)
                    acc[i][j] = __builtin_amdgcn_mfma_f32_16x16x32_bf16(af[i], bfr[j], acc[i][j], 0, 0, 0);
        }
        __syncthreads();
    }

    float wv4[4];
    #pragma unroll
    for (int j = 0; j < 4; ++j) wv4[j] = nw[n0 + j*16 + l16];
    #pragma unroll
    for (int i = 0; i < 2; ++i) {
        float ss[4];
        #pragma unroll
        for (int r = 0; r < 4; ++r) {
            float s = 0.f;
            #pragma unroll
            for (int j = 0; j < 4; ++j) s += acc[i][j][r] * acc[i][j][r];
            ss[r] = s;
        }
        #pragma unroll
        for (int off = 1; off < 16; off <<= 1)
            #pragma unroll
            for (int r = 0; r < 4; ++r) ss[r] += __shfl_xor(ss[r], off, 64);
        float sc[4];
        #pragma unroll
        for (int r = 0; r < 4; ++r) sc[r] = rsqrtf(ss[r] * (1.f/64.f) + EPSF);
        #pragma unroll
        for (int r = 0; r < 4; ++r) {
            u16* yp = Y + (size_t)(m0 + w*32 + i*16 + quad*4 + r) * N + n0;
            #pragma unroll
            for (int j = 0; j < 4; ++j)
                yp[j*16 + l16] = f2bf(acc[i][j][r] * sc[r] * wv4[j]);
        }
    }
}

// ---------------- out_mega: block (bh, c) computes its own S-prefix by
// MFMA-accumulating V_{c'}^T K_{c'} for c' < c (fp32, exact), then
// out = tril(Q K^T) @ V + Q @ S0. No kv_scan kernel, no S buffer.
__global__ __launch_bounds__(256) void out_mega(const u16* __restrict__ Xb,
                                                const u16* __restrict__ Qb,
                                                const u16* __restrict__ Vb,
                                                float* __restrict__ out)
{
    const int c = 15 - (blockIdx.x & 15);   // heavy blocks first
    const int bh = blockIdx.x >> 4;
    const int h = bh & 15, b = bh >> 4;
    __shared__ u16 Qs[64][72];    // [l][d]
    __shared__ u16 Ko[64][72];    // own K [l'][d]  -> later Ps [l][l']
    __shared__ u16 Vo[64][72];    // own V^T [e][l']
    __shared__ u16 St[64][72];    // S0^T [e][d] bf16
    __shared__ u16 Kt[64][72];    // loop staging K^T [d][l]
    __shared__ u16 Vt[64][72];    // loop staging V^T [e][l]
    const int tid = threadIdx.x;
    const int row = tid >> 2, q = tid & 3;
    const int w = tid >> 6, lane = tid & 63, quad = lane >> 4, l16 = lane & 15;

    // stage own chunk: Q[l][d], K[l'][d], V^T[e][l']
    {
        size_t gbase = (size_t)(b*LL + c*64 + row) * DD + h*64 + q*16;
        u16 vv[16];
        #pragma unroll
        for (int i = 0; i < 16; i += 4) {
            *(ushort4*)&Qs[row][q*16 + i] = *(const ushort4*)(Qb + gbase + i);
            *(ushort4*)&Ko[row][q*16 + i] = *(const ushort4*)(Xb + gbase + i);
            *(ushort4*)&vv[i] = *(const ushort4*)(Vb + gbase + i);
        }
        #pragma unroll
        for (int i = 0; i < 16; ++i)
            Vo[q*16 + i][row] = vv[i];
    }

    // S^T prefix accumulation over earlier chunks, software-pipelined
    const int we = (w & 1) * 32, wd = (w >> 1) * 32;
    f32x4 sacc[2][2] = {};
    const u16* gK = Xb + (size_t)(b*LL + row) * DD + h*64 + q*16;
    const u16* gV = Vb + (size_t)(b*LL + row) * DD + h*64 + q*16;
    ushort4 kr[4], vr[4];
    if (c > 0) {
        #pragma unroll
        for (int i = 0; i < 4; ++i) {
            kr[i] = *(const ushort4*)(gK + i*4);
            vr[i] = *(const ushort4*)(gV + i*4);
        }
    }
    __syncthreads();   // own-chunk staging visible (also covers c==0 path)
    for (int cp = 0; cp < c; ++cp) {
        #pragma unroll
        for (int i = 0; i < 16; ++i) {
            Kt[q*16 + i][row] = ((const u16*)kr)[i];
            Vt[q*16 + i][row] = ((const u16*)vr)[i];
        }
        __syncthreads();
        if (cp + 1 < c) {
            const u16* nK = gK + (size_t)(cp+1)*64*DD;
            const u16* nV = gV + (size_t)(cp+1)*64*DD;
            #pragma unroll
            for (int i = 0; i < 4; ++i) {
                kr[i] = *(const ushort4*)(nK + i*4);
                vr[i] = *(const ushort4*)(nV + i*4);
            }
        }
        #pragma unroll
        for (int k0 = 0; k0 < 64; k0 += 32) {
            bf16x8 av[2], bv[2];
            #pragma unroll
            for (int i = 0; i < 2; ++i)
                av[i] = *(const bf16x8*)&Vt[we + i*16 + l16][k0 + quad*8];
            #pragma unroll
            for (int j = 0; j < 2; ++j)
                bv[j] = *(const bf16x8*)&Kt[wd + j*16 + l16][k0 + quad*8];
            #pragma unroll
            for (int i = 0; i < 2; ++i)
                #pragma unroll
                for (int j = 0; j < 2; ++j)
                    sacc[i][j] = __builtin_amdgcn_mfma_f32_16x16x32_bf16(av[i], bv[j], sacc[i][j], 0, 0, 0);
        }
        __syncthreads();
    }

    // write S0^T bf16 tile (each wave its (e,d) quadrant, C-layout)
    #pragma unroll
    for (int i = 0; i < 2; ++i)
        #pragma unroll
        for (int j = 0; j < 2; ++j)
            #pragma unroll
            for (int r = 0; r < 4; ++r)
                St[we + i*16 + quad*4 + r][wd + j*16 + l16] = f2bf(sacc[i][j][r]);

    // P = Q K^T, causal-masked, bf16 (Ps aliases Ko)
    const int mo = (w & 1) * 32, no = (w >> 1) * 32;
    f32x4 pacc[2][2] = {};
    #pragma unroll
    for (int k0 = 0; k0 < 64; k0 += 32) {
        bf16x8 aq[2], bk[2];
        #pragma unroll
        for (int i = 0; i < 2; ++i)
            aq[i] = *(const bf16x8*)&Qs[mo + i*16 + l16][k0 + quad*8];
        #pragma unroll
        for (int j = 0; j < 2; ++j)
            bk[j] = *(const bf16x8*)&Ko[no + j*16 + l16][k0 + quad*8];
        #pragma unroll
        for (int i = 0; i < 2; ++i)
            #pragma unroll
            for (int j = 0; j < 2; ++j)
                pacc[i][j] = __builtin_amdgcn_mfma_f32_16x16x32_bf16(aq[i], bk[j], pacc[i][j], 0, 0, 0);
    }
    __syncthreads();   // P-reads of Ko done; St writes visible
    #pragma unroll
    for (int i = 0; i < 2; ++i)
        #pragma unroll
        for (int j = 0; j < 2; ++j)
            #pragma unroll
            for (int r = 0; r < 4; ++r) {
                int l  = mo + i*16 + quad*4 + r;
                int lp = no + j*16 + l16;
                Ko[l][lp] = (lp <= l) ? f2bf(pacc[i][j][r]) : (u16)0;   // Ps
            }
    __syncthreads();

    // O = P @ V + Q @ S0
    f32x4 acc[2][2] = {};
    #pragma unroll
    for (int k0 = 0; k0 < 64; k0 += 32) {
        bf16x8 a1[2], b1[2], a2[2], b2[2];
        #pragma unroll
        for (int i = 0; i < 2; ++i) {
            a1[i] = *(const bf16x8*)&Ko[mo + i*16 + l16][k0 + quad*8];
            a2[i] = *(const bf16x8*)&Qs[mo + i*16 + l16][k0 + quad*8];
        }
        #pragma unroll
        for (int j = 0; j < 2; ++j) {
            b1[j] = *(const bf16x8*)&Vo[no + j*16 + l16][k0 + quad*8];
            b2[j] = *(const bf16x8*)&St[no + j*16 + l16][k0 + quad*8];
        }
        #pragma unroll
        for (int i = 0; i < 2; ++i)
            #pragma unroll
            for (int j = 0; j < 2; ++j) {
                acc[i][j] = __builtin_amdgcn_mfma_f32_16x16x32_bf16(a1[i], b1[j], acc[i][j], 0, 0, 0);
                acc[i][j] = __builtin_amdgcn_mfma_f32_16x16x32_bf16(a2[i], b2[j], acc[i][j], 0, 0, 0);
            }
    }
    float* op = out + (size_t)(b*LL + c*64) * DD + h*64;
    #pragma unroll
    for (int i = 0; i < 2; ++i)
        #pragma unroll
        for (int j = 0; j < 2; ++j)
            #pragma unroll
            for (int r = 0; r < 4; ++r)
                op[(size_t)(mo + i*16 + quad*4 + r) * DD + no + j*16 + l16] = acc[i][j][r];
}

extern "C" void kernel_launch(void* const* d_in, const int* in_sizes, int n_in,
                              void* d_out, int out_size, void* d_ws, size_t ws_size,
                              hipStream_t stream) {
    const float* X  = (const float*)d_in[0];
    const float* Wq = (const float*)d_in[1];
    const float* Wv = (const float*)d_in[2];
    const float* qw = (const float*)d_in[3];
    const float* vw = (const float*)d_in[4];
    float* out = (float*)d_out;

    u16* Xb  = (u16*)d_ws;                        // 2M u16
    u16* Wqb = Xb  + (size_t)2*1024*1024;         // 1M
    u16* Wvb = Wqb + (size_t)1024*1024;           // 1M
    u16* Qb  = Wvb + (size_t)1024*1024;           // 2M
    u16* Vb  = Qb  + (size_t)2*1024*1024;         // 2M

    cvt_k<<<4096, 256, 0, stream>>>(X, Wq, Wv, Xb, Wqb, Wvb);
    gemm_fused<<<dim3(16, 16, 2), 256, 0, stream>>>(Xb, Wqb, Wvb, qw, vw, Qb, Vb);
    out_mega<<<BB*HH*NC, 256, 0, stream>>>(Xb, Qb, Vb, out);
}

// Round 9
// 101.929 us; speedup vs baseline: 3.4521x; 1.1065x over previous
//
#include <hip/hip_runtime.h>

#define BB 2
#define LL 1024
#define DD 1024
#define HH 16
#define NC 16
#define EPSF 1e-8f

typedef __attribute__((ext_vector_type(8))) short bf16x8;
typedef __attribute__((ext_vector_type(4))) float f32x4;
typedef unsigned short u16;

static __device__ inline u16 f2bf(float f) {
    unsigned int u = __builtin_bit_cast(unsigned int, f);
    u += 0x7fff + ((u >> 16) & 1);     // RNE
    return (u16)(u >> 16);
}
static __device__ inline float bf2f(u16 v) {
    unsigned int u = ((unsigned int)v) << 16;
    return __builtin_bit_cast(float, u);
}
static __device__ inline void gload_lds16(const u16* g, u16* l) {
    __builtin_amdgcn_global_load_lds((const __attribute__((address_space(1))) void*)g,
                                     (__attribute__((address_space(3))) void*)l, 16, 0, 0);
}

// ---------------- fp32 -> bf16 convert: X (2M), Wq (1M), Wv (1M)
__global__ __launch_bounds__(256) void cvt_k(const float* __restrict__ X,
                                             const float* __restrict__ Wq,
                                             const float* __restrict__ Wv,
                                             u16* __restrict__ Xb,
                                             u16* __restrict__ Wqb,
                                             u16* __restrict__ Wvb)
{
    int i = (blockIdx.x * 256 + threadIdx.x) * 4;
    const float* s; u16* d; int off;
    if (i < 2*1024*1024)      { s = X;  d = Xb;  off = i; }
    else if (i < 3*1024*1024) { s = Wq; d = Wqb; off = i - 2*1024*1024; }
    else                      { s = Wv; d = Wvb; off = i - 3*1024*1024; }
    float4 v = *(const float4*)(s + off);
    ushort4 o;
    o.x = f2bf(v.x); o.y = f2bf(v.y); o.z = f2bf(v.z); o.w = f2bf(v.w);
    *(ushort4*)(d + off) = o;
}

// ---------------- bf16 MFMA GEMM + fused per-head RMSNorm, bf16 out.
// 128(M) x 64(N) tile, BK=64 via two ping LDS slices; 512 blocks (2/CU).
__global__ __launch_bounds__(256) void gemm_fused(const u16* __restrict__ Xb,
                                                  const u16* __restrict__ Wqb,
                                                  const u16* __restrict__ Wvb,
                                                  const float* __restrict__ qw,
                                                  const float* __restrict__ vw,
                                                  u16* __restrict__ Qb,
                                                  u16* __restrict__ Vb)
{
    const int K = DD, N = DD;
    const u16* W = blockIdx.z ? Wvb : Wqb;
    const float* nw = blockIdx.z ? vw : qw;
    u16* Y = blockIdx.z ? Vb : Qb;
    __shared__ u16 As0[128 * 32], As1[128 * 32];
    __shared__ u16 Bs0[64 * 32],  Bs1[64 * 32];

    const int tid = threadIdx.x, w = tid >> 6, lane = tid & 63;
    const int quad = lane >> 4, l16 = lane & 15;
    const int m0 = blockIdx.y * 128, n0 = blockIdx.x * 64;
    const int lrow = lane >> 2, lcol = (lane & 3) * 8;

    const u16* gA0 = Xb + (size_t)(m0 + w*16 + lrow) * K + lcol;
    const u16* gA1 = gA0 + (size_t)64 * K;
    const u16* gB0 = W + (size_t)(n0 + w*16 + lrow) * K + lcol;
    u16* lA0_0 = &As0[(w*16) * 32];      u16* lA0_1 = &As1[(w*16) * 32];
    u16* lA1_0 = &As0[(64 + w*16) * 32]; u16* lA1_1 = &As1[(64 + w*16) * 32];
    u16* lB0_0 = &Bs0[(w*16) * 32];      u16* lB0_1 = &Bs1[(w*16) * 32];

    f32x4 acc[2][4] = {};
    for (int k0 = 0; k0 < K; k0 += 64) {
        gload_lds16(gA0 + k0,      lA0_0);
        gload_lds16(gA0 + k0 + 32, lA0_1);
        gload_lds16(gA1 + k0,      lA1_0);
        gload_lds16(gA1 + k0 + 32, lA1_1);
        gload_lds16(gB0 + k0,      lB0_0);
        gload_lds16(gB0 + k0 + 32, lB0_1);
        __syncthreads();
        #pragma unroll
        for (int hh = 0; hh < 2; ++hh) {
            const u16* Ah = hh ? As1 : As0;
            const u16* Bh = hh ? Bs1 : Bs0;
            bf16x8 af[2], bfr[4];
            #pragma unroll
            for (int i = 0; i < 2; ++i)
                af[i] = *(const bf16x8*)&Ah[(w*32 + i*16 + l16) * 32 + quad*8];
            #pragma unroll
            for (int j = 0; j < 4; ++j)
                bfr[j] = *(const bf16x8*)&Bh[(j*16 + l16) * 32 + quad*8];
            #pragma unroll
            for (int i = 0; i < 2; ++i)
                #pragma unroll
                for (int j = 0; j < 4; ++j)
                    acc[i][j] = __builtin_amdgcn_mfma_f32_16x16x32_bf16(af[i], bfr[j], acc[i][j], 0, 0, 0);
        }
        __syncthreads();
    }

    float wv4[4];
    #pragma unroll
    for (int j = 0; j < 4; ++j) wv4[j] = nw[n0 + j*16 + l16];
    #pragma unroll
    for (int i = 0; i < 2; ++i) {
        float ss[4];
        #pragma unroll
        for (int r = 0; r < 4; ++r) {
            float s = 0.f;
            #pragma unroll
            for (int j = 0; j < 4; ++j) s += acc[i][j][r] * acc[i][j][r];
            ss[r] = s;
        }
        #pragma unroll
        for (int off = 1; off < 16; off <<= 1)
            #pragma unroll
            for (int r = 0; r < 4; ++r) ss[r] += __shfl_xor(ss[r], off, 64);
        float sc[4];
        #pragma unroll
        for (int r = 0; r < 4; ++r) sc[r] = rsqrtf(ss[r] * (1.f/64.f) + EPSF);
        #pragma unroll
        for (int r = 0; r < 4; ++r) {
            u16* yp = Y + (size_t)(m0 + w*32 + i*16 + quad*4 + r) * N + n0;
            #pragma unroll
            for (int j = 0; j < 4; ++j)
                yp[j*16 + l16] = f2bf(acc[i][j][r] * sc[r] * wv4[j]);
        }
    }
}

// ---------------- per-chunk S_c^T[e][d] = V_c^T K_c, fully parallel (512 blk)
// Stored bf16, flat MFMA C-layout: f = w*1024 + (i*2+j)*256 + r*64 + lane
//   e = (w&1)*32 + i*16 + (lane>>4)*4 + r ; d = (w>>1)*32 + j*16 + (lane&15)
__global__ __launch_bounds__(256) void kv_chunk(const u16* __restrict__ Xb,
                                                const u16* __restrict__ Vb,
                                                u16* __restrict__ S)
{
    const int c = blockIdx.x & 15, bh = blockIdx.x >> 4;
    const int h = bh & 15, b = bh >> 4;
    __shared__ u16 Kt[64][72];   // [d][l]
    __shared__ u16 Vt[64][72];   // [e][l]
    const int tid = threadIdx.x;
    {
        const int row = tid >> 2, q = tid & 3;
        size_t gbase = (size_t)(b*LL + c*64 + row) * DD + h*64 + q*16;
        u16 kk[16], vv[16];
        #pragma unroll
        for (int i = 0; i < 16; i += 4) {
            *(ushort4*)&kk[i] = *(const ushort4*)(Xb + gbase + i);
            *(ushort4*)&vv[i] = *(const ushort4*)(Vb + gbase + i);
        }
        #pragma unroll
        for (int i = 0; i < 16; ++i) {
            Kt[q*16 + i][row] = kk[i];
            Vt[q*16 + i][row] = vv[i];
        }
    }
    __syncthreads();
    const int w = tid >> 6, lane = tid & 63, quad = lane >> 4, l16 = lane & 15;
    const int me = (w & 1) * 32, nd = (w >> 1) * 32;
    f32x4 acc[2][2] = {};
    #pragma unroll
    for (int k0 = 0; k0 < 64; k0 += 32) {
        bf16x8 av[2], bv[2];
        #pragma unroll
        for (int i = 0; i < 2; ++i)
            av[i] = *(const bf16x8*)&Vt[me + i*16 + l16][k0 + quad*8];
        #pragma unroll
        for (int j = 0; j < 2; ++j)
            bv[j] = *(const bf16x8*)&Kt[nd + j*16 + l16][k0 + quad*8];
        #pragma unroll
        for (int i = 0; i < 2; ++i)
            #pragma unroll
            for (int j = 0; j < 2; ++j)
                acc[i][j] = __builtin_amdgcn_mfma_f32_16x16x32_bf16(av[i], bv[j], acc[i][j], 0, 0, 0);
    }
    u16* Sp = S + ((size_t)blockIdx.x << 12) + w*1024;
    #pragma unroll
    for (int i = 0; i < 2; ++i)
        #pragma unroll
        for (int j = 0; j < 2; ++j)
            #pragma unroll
            for (int r = 0; r < 4; ++r)
                Sp[(i*2 + j)*256 + r*64 + lane] = f2bf(acc[i][j][r]);
}

// ---------------- out = tril(Q K^T) @ V + Q @ S0; block sums its own prefix
// from the parallel per-chunk S tiles (L2-resident, avg 7.5 x 8 KB).
__global__ __launch_bounds__(256) void out_k2(const u16* __restrict__ Xb,
                                              const u16* __restrict__ Qb,
                                              const u16* __restrict__ Vb,
                                              const u16* __restrict__ S,
                                              float* __restrict__ out)
{
    const int c = 15 - (blockIdx.x & 15);   // heavy (large-c) blocks first
    const int bh = blockIdx.x >> 4;
    const int h = bh & 15, b = bh >> 4;
    __shared__ u16 Qs[64][72];   // [l][d]
    __shared__ u16 Ks[64][72];   // [l'][d] -> later Ps [l][l']
    __shared__ u16 Vt[64][72];   // [e][l']
    __shared__ u16 St[64][72];   // [e][d]  summed prefix, bf16
    const int tid = threadIdx.x;
    {
        const int row = tid >> 2, q = tid & 3;
        size_t gbase = (size_t)(b*LL + c*64 + row) * DD + h*64 + q*16;
        u16 vv[16];
        #pragma unroll
        for (int i = 0; i < 16; i += 4) {
            *(ushort4*)&Qs[row][q*16 + i] = *(const ushort4*)(Qb + gbase + i);
            *(ushort4*)&Ks[row][q*16 + i] = *(const ushort4*)(Xb + gbase + i);
            *(ushort4*)&vv[i] = *(const ushort4*)(Vb + gbase + i);
        }
        #pragma unroll
        for (int i = 0; i < 16; ++i)
            Vt[q*16 + i][row] = vv[i];
        // prefix sum of earlier chunk tiles: 16 fp32 accumulators per thread
        float facc[16] = {};
        const u16* Sbase = S + ((size_t)(bh * NC) << 12);
        for (int cp = 0; cp < c; ++cp) {
            const u16* Sc = Sbase + ((size_t)cp << 12);
            #pragma unroll
            for (int jj = 0; jj < 4; ++jj) {
                ushort4 sv = *(const ushort4*)(Sc + tid*4 + jj*1024);
                facc[jj*4+0] += bf2f(sv.x);
                facc[jj*4+1] += bf2f(sv.y);
                facc[jj*4+2] += bf2f(sv.z);
                facc[jj*4+3] += bf2f(sv.w);
            }
        }
        // decode flat C-layout and write St[e][d..d+3]
        #pragma unroll
        for (int jj = 0; jj < 4; ++jj) {
            int g = tid * 4;                 // offset within the 1024-elem quadrant
            int ij = (g >> 8) & 3, r = (g >> 6) & 3, ln = g & 63;
            int e = (jj & 1)*32 + (ij >> 1)*16 + (ln >> 4)*4 + r;
            int d = (jj >> 1)*32 + (ij & 1)*16 + (ln & 15);
            ushort4 o;
            o.x = f2bf(facc[jj*4+0]);
            o.y = f2bf(facc[jj*4+1]);
            o.z = f2bf(facc[jj*4+2]);
            o.w = f2bf(facc[jj*4+3]);
            *(ushort4*)&St[e][d] = o;
        }
    }
    __syncthreads();
    const int w = tid >> 6, lane = tid & 63, quad = lane >> 4, l16 = lane & 15;
    const int mo = (w & 1) * 32, no = (w >> 1) * 32;

    // P = Q K^T, causal-masked, bf16 (Ps aliases Ks)
    f32x4 pacc[2][2] = {};
    #pragma unroll
    for (int k0 = 0; k0 < 64; k0 += 32) {
        bf16x8 aq[2], bk[2];
        #pragma unroll
        for (int i = 0; i < 2; ++i)
            aq[i] = *(const bf16x8*)&Qs[mo + i*16 + l16][k0 + quad*8];
        #pragma unroll
        for (int j = 0; j < 2; ++j)
            bk[j] = *(const bf16x8*)&Ks[no + j*16 + l16][k0 + quad*8];
        #pragma unroll
        for (int i = 0; i < 2; ++i)
            #pragma unroll
            for (int j = 0; j < 2; ++j)
                pacc[i][j] = __builtin_amdgcn_mfma_f32_16x16x32_bf16(aq[i], bk[j], pacc[i][j], 0, 0, 0);
    }
    __syncthreads();
    #pragma unroll
    for (int i = 0; i < 2; ++i)
        #pragma unroll
        for (int j = 0; j < 2; ++j)
            #pragma unroll
            for (int r = 0; r < 4; ++r) {
                int l  = mo + i*16 + quad*4 + r;
                int lp = no + j*16 + l16;
                Ks[l][lp] = (lp <= l) ? f2bf(pacc[i][j][r]) : (u16)0;
            }
    __syncthreads();

    // O = P @ V + Q @ S0
    f32x4 acc[2][2] = {};
    #pragma unroll
    for (int k0 = 0; k0 < 64; k0 += 32) {
        bf16x8 a1[2], b1[2], a2[2], b2[2];
        #pragma unroll
        for (int i = 0; i < 2; ++i) {
            a1[i] = *(const bf16x8*)&Ks[mo + i*16 + l16][k0 + quad*8];
            a2[i] = *(const bf16x8*)&Qs[mo + i*16 + l16][k0 + quad*8];
        }
        #pragma unroll
        for (int j = 0; j < 2; ++j) {
            b1[j] = *(const bf16x8*)&Vt[no + j*16 + l16][k0 + quad*8];
            b2[j] = *(const bf16x8*)&St[no + j*16 + l16][k0 + quad*8];
        }
        #pragma unroll
        for (int i = 0; i < 2; ++i)
            #pragma unroll
            for (int j = 0; j < 2; ++j) {
                acc[i][j] = __builtin_amdgcn_mfma_f32_16x16x32_bf16(a1[i], b1[j], acc[i][j], 0, 0, 0);
                acc[i][j] = __builtin_amdgcn_mfma_f32_16x16x32_bf16(a2[i], b2[j], acc[i][j], 0, 0, 0);
            }
    }
    float* op = out + (size_t)(b*LL + c*64) * DD + h*64;
    #pragma unroll
    for (int i = 0; i < 2; ++i)
        #pragma unroll
        for (int j = 0; j < 2; ++j)
            #pragma unroll
            for (int r = 0; r < 4; ++r)
                op[(size_t)(mo + i*16 + quad*4 + r) * DD + no + j*16 + l16] = acc[i][j][r];
}

extern "C" void kernel_launch(void* const* d_in, const int* in_sizes, int n_in,
                              void* d_out, int out_size, void* d_ws, size_t ws_size,
                              hipStream_t stream) {
    const float* X  = (const float*)d_in[0];
    const float* Wq = (const float*)d_in[1];
    const float* Wv = (const float*)d_in[2];
    const float* qw = (const float*)d_in[3];
    const float* vw = (const float*)d_in[4];
    float* out = (float*)d_out;

    u16* Xb  = (u16*)d_ws;                        // 2M u16
    u16* Wqb = Xb  + (size_t)2*1024*1024;         // 1M
    u16* Wvb = Wqb + (size_t)1024*1024;           // 1M
    u16* Qb  = Wvb + (size_t)1024*1024;           // 2M
    u16* Vb  = Qb  + (size_t)2*1024*1024;         // 2M
    u16* S   = Vb  + (size_t)2*1024*1024;         // 2M u16

    cvt_k<<<4096, 256, 0, stream>>>(X, Wq, Wv, Xb, Wqb, Wvb);
    gemm_fused<<<dim3(16, 16, 2), 256, 0, stream>>>(Xb, Wqb, Wvb, qw, vw, Qb, Vb);
    kv_chunk<<<BB*HH*NC, 256, 0, stream>>>(Xb, Vb, S);
    out_k2<<<BB*HH*NC, 256, 0, stream>>>(Xb, Qb, Vb, S, out);
}